// Round 6
// baseline (87.607 us; speedup 1.0000x reference)
//
#include <hip/hip_runtime.h>
#include <math.h>

// NoisyTopKGating via fp16x2-split MFMA, barrier-free K-loop.
// Each wave: 32 rows x 32 cols, A-frags loaded direct from global with in-register
// f16 hi/lo split; B from fragment-packed workspace (1KB contiguous per wave-load).
// out layout (f32 flat): weights [N,2] @0, indices-as-float [N,2] @32768, clean [N,64] @65536.
// d_ws: Bh packed frags (512KB) @0, Bl packed frags (512KB) @+262144 f16.
// Packed layout (f16 units): [(kc*8 + wid*2 + cf)*512 + lane*8 + j]
//   col = wid*32 + cf*16 + (lane&15),  k = kc*32 + (lane>>4)*8 + j.

constexpr int NROWS = 16384;
constexpr int DDIM  = 2048;
constexpr int EDIM  = 64;
constexpr int BM    = 32;             // rows per block
constexpr int NKS   = 64;             // k-steps of 32
constexpr int LSTR  = 132;            // epilogue LDS stride (floats)
constexpr int IDX_OFF   = NROWS * 2;
constexpr int CLEAN_OFF = NROWS * 4;
constexpr size_t WPACK = 262144;      // f16 elements per packed matrix (128*2048)

typedef _Float16 f16x8 __attribute__((ext_vector_type(8)));
typedef float    f32x4 __attribute__((ext_vector_type(4)));

__device__ __forceinline__ float softplus_f(float z) {
    return fmaxf(z, 0.0f) + log1pf(expf(-fabsf(z)));
}

// ---------- pre-kernel: split + pack weights into per-wave-coalesced MFMA frags ----------
__global__ __launch_bounds__(256) void split_w_kernel(
    const float* __restrict__ Wg, const float* __restrict__ Wn,
    _Float16* __restrict__ wh, _Float16* __restrict__ wl)
{
    const int t    = blockIdx.x * 256 + threadIdx.x;   // 0..32767
    const int grp  = t >> 6;                           // kc*8 + wid*2 + cf  (0..511)
    const int lane = t & 63;
    const int kc   = grp >> 3;
    const int wid  = (grp >> 1) & 3;
    const int cf   = grp & 1;
    const int col  = wid * 32 + cf * 16 + (lane & 15);
    const int k0   = kc * 32 + (lane >> 4) * 8;
    const float* src = (col < 64) ? &Wg[(size_t)col * DDIM + k0]
                                  : &Wn[(size_t)(col - 64) * DDIM + k0];
    const float4 v0 = *reinterpret_cast<const float4*>(src);
    const float4 v1 = *reinterpret_cast<const float4*>(src + 4);
    float vv[8] = {v0.x, v0.y, v0.z, v0.w, v1.x, v1.y, v1.z, v1.w};
    union { _Float16 h[8]; uint4 u; } hh, ll;
    #pragma unroll
    for (int j = 0; j < 8; ++j) {
        hh.h[j] = (_Float16)vv[j];
        ll.h[j] = (_Float16)((vv[j] - (float)hh.h[j]) * 2048.0f);
    }
    const size_t off = (size_t)grp * 512 + lane * 8;
    *reinterpret_cast<uint4*>(&wh[off]) = hh.u;
    *reinterpret_cast<uint4*>(&wl[off]) = ll.u;
}

__device__ __forceinline__ void split8(const float4 a, const float4 b, f16x8& h, f16x8& l) {
    const float v[8] = {a.x, a.y, a.z, a.w, b.x, b.y, b.z, b.w};
    #pragma unroll
    for (int j = 0; j < 8; ++j) {
        const _Float16 hh = (_Float16)v[j];
        h[j] = hh;
        l[j] = (_Float16)((v[j] - (float)hh) * 2048.0f);
    }
}

// ---------- main fused kernel ----------
__global__ __launch_bounds__(256, 2) void gating_mfma_kernel(
    const float* __restrict__ x,
    const float* __restrict__ noise,
    const _Float16* __restrict__ whp,
    const _Float16* __restrict__ wlp,
    float* __restrict__ out)
{
    __shared__ float L[BM * LSTR];       // epilogue exchange only (16.9 KB)

    const int tid = threadIdx.x;
    const int row_base = blockIdx.x * BM;
    const int lane = tid & 63;
    const int wid  = tid >> 6;           // 0..3
    const int g    = lane >> 4;          // k-group 0..3
    const int idx  = lane & 15;
    const int colbase = wid * 32;

    // A pointers: lane reads rows idx and idx+16, k-elems g*8..g*8+7 per k-step
    const float* a0 = x + (size_t)(row_base + idx) * DDIM + g * 8;
    const float* a1 = a0 + (size_t)16 * DDIM;

    // B base pointers (fragment-packed; per-wave 1KB contiguous per load)
    const _Float16* bh = whp + (size_t)wid * 1024 + lane * 8;
    const _Float16* bl = wlp + (size_t)wid * 1024 + lane * 8;

    f32x4 accm[2][2], accc[2][2];
    #pragma unroll
    for (int rf = 0; rf < 2; ++rf)
        #pragma unroll
        for (int cf = 0; cf < 2; ++cf) { accm[rf][cf] = (f32x4)0.0f; accc[rf][cf] = (f32x4)0.0f; }

    auto loadA = [&](int ks, float4& A0a, float4& A0b, float4& A1a, float4& A1b) {
        const float* p = a0 + ks * 32;
        A0a = *reinterpret_cast<const float4*>(p);
        A0b = *reinterpret_cast<const float4*>(p + 4);
        const float* q = a1 + ks * 32;
        A1a = *reinterpret_cast<const float4*>(q);
        A1b = *reinterpret_cast<const float4*>(q + 4);
    };
    auto loadB = [&](int ks, f16x8& Bh0, f16x8& Bh1, f16x8& Bl0, f16x8& Bl1) {
        const _Float16* p = bh + (size_t)ks * 4096;
        Bh0 = *reinterpret_cast<const f16x8*>(p);
        Bh1 = *reinterpret_cast<const f16x8*>(p + 512);
        const _Float16* q = bl + (size_t)ks * 4096;
        Bl0 = *reinterpret_cast<const f16x8*>(q);
        Bl1 = *reinterpret_cast<const f16x8*>(q + 512);
    };

    // ---- 2-slot, distance-2 register pipeline; no LDS, no barriers ----
    float4 qa0[2], qb0[2], qa1[2], qb1[2];
    f16x8  rh0[2], rh1[2], rl0[2], rl1[2];
    loadA(0, qa0[0], qb0[0], qa1[0], qb1[0]);
    loadB(0, rh0[0], rh1[0], rl0[0], rl1[0]);
    loadA(1, qa0[1], qb0[1], qa1[1], qb1[1]);
    loadB(1, rh0[1], rh1[1], rl0[1], rl1[1]);

    for (int t = 0; t < NKS / 2; ++t) {
        #pragma unroll
        for (int p = 0; p < 2; ++p) {
            const int ks = 2 * t + p;
            // convert current slot (must precede slot overwrite)
            f16x8 Ah0, Al0, Ah1, Al1;
            split8(qa0[p], qb0[p], Ah0, Al0);
            split8(qa1[p], qb1[p], Ah1, Al1);
            const f16x8 Bh0 = rh0[p], Bh1 = rh1[p], Bl0 = rl0[p], Bl1 = rl1[p];
            // issue distance-2 prefetch before the MFMA cluster
            if (ks < NKS - 2) {
                loadA(ks + 2, qa0[p], qb0[p], qa1[p], qb1[p]);
                loadB(ks + 2, rh0[p], rh1[p], rl0[p], rl1[p]);
            }
            accm[0][0] = __builtin_amdgcn_mfma_f32_16x16x32_f16(Ah0, Bh0, accm[0][0], 0, 0, 0);
            accm[0][1] = __builtin_amdgcn_mfma_f32_16x16x32_f16(Ah0, Bh1, accm[0][1], 0, 0, 0);
            accm[1][0] = __builtin_amdgcn_mfma_f32_16x16x32_f16(Ah1, Bh0, accm[1][0], 0, 0, 0);
            accm[1][1] = __builtin_amdgcn_mfma_f32_16x16x32_f16(Ah1, Bh1, accm[1][1], 0, 0, 0);
            accc[0][0] = __builtin_amdgcn_mfma_f32_16x16x32_f16(Al0, Bh0, accc[0][0], 0, 0, 0);
            accc[0][1] = __builtin_amdgcn_mfma_f32_16x16x32_f16(Al0, Bh1, accc[0][1], 0, 0, 0);
            accc[1][0] = __builtin_amdgcn_mfma_f32_16x16x32_f16(Al1, Bh0, accc[1][0], 0, 0, 0);
            accc[1][1] = __builtin_amdgcn_mfma_f32_16x16x32_f16(Al1, Bh1, accc[1][1], 0, 0, 0);
            accc[0][0] = __builtin_amdgcn_mfma_f32_16x16x32_f16(Ah0, Bl0, accc[0][0], 0, 0, 0);
            accc[0][1] = __builtin_amdgcn_mfma_f32_16x16x32_f16(Ah0, Bl1, accc[0][1], 0, 0, 0);
            accc[1][0] = __builtin_amdgcn_mfma_f32_16x16x32_f16(Ah1, Bl0, accc[1][0], 0, 0, 0);
            accc[1][1] = __builtin_amdgcn_mfma_f32_16x16x32_f16(Ah1, Bl1, accc[1][1], 0, 0, 0);
        }
    }

    // ---- epilogue: logits -> LDS [32][132] f32 ----
    #pragma unroll
    for (int rf = 0; rf < 2; ++rf)
        #pragma unroll
        for (int cf = 0; cf < 2; ++cf) {
            const int col = colbase + cf * 16 + idx;
            #pragma unroll
            for (int q = 0; q < 4; ++q) {
                const int lrow = rf * 16 + g * 4 + q;
                L[lrow * LSTR + col] = accm[rf][cf][q] + accc[rf][cf][q] * 4.8828125e-4f;
            }
        }
    __syncthreads();

    // ---- fused softplus/noise/top-2/softmax: 8 threads per row ----
    {
        const int row = tid >> 3;
        const int j   = tid & 7;
        const int e0  = j * 8;
        const int grow = row_base + row;

        const float4 c0 = *reinterpret_cast<const float4*>(&L[row * LSTR + e0]);
        const float4 c1 = *reinterpret_cast<const float4*>(&L[row * LSTR + e0 + 4]);
        const float4 s0 = *reinterpret_cast<const float4*>(&L[row * LSTR + 64 + e0]);
        const float4 s1 = *reinterpret_cast<const float4*>(&L[row * LSTR + 64 + e0 + 4]);
        *reinterpret_cast<float4*>(&out[CLEAN_OFF + (size_t)grow * EDIM + e0])     = c0;
        *reinterpret_cast<float4*>(&out[CLEAN_OFF + (size_t)grow * EDIM + e0 + 4]) = c1;

        const float4 z0 = *reinterpret_cast<const float4*>(&noise[(size_t)grow * EDIM + e0]);
        const float4 z1 = *reinterpret_cast<const float4*>(&noise[(size_t)grow * EDIM + e0 + 4]);

        float nv[8];
        nv[0] = fmaf(softplus_f(s0.x), z0.x, c0.x);
        nv[1] = fmaf(softplus_f(s0.y), z0.y, c0.y);
        nv[2] = fmaf(softplus_f(s0.z), z0.z, c0.z);
        nv[3] = fmaf(softplus_f(s0.w), z0.w, c0.w);
        nv[4] = fmaf(softplus_f(s1.x), z1.x, c1.x);
        nv[5] = fmaf(softplus_f(s1.y), z1.y, c1.y);
        nv[6] = fmaf(softplus_f(s1.z), z1.z, c1.z);
        nv[7] = fmaf(softplus_f(s1.w), z1.w, c1.w);

        float v0 = nv[0], v1 = -INFINITY;
        int   i0 = e0,    i1 = -1;
        #pragma unroll
        for (int m = 1; m < 8; ++m) {
            const float v = nv[m]; const int e = e0 + m;
            if (v > v0)      { v1 = v0; i1 = i0; v0 = v; i0 = e; }
            else if (v > v1) { v1 = v;  i1 = e; }
        }
        #pragma unroll
        for (int d = 1; d < 8; d <<= 1) {
            const float ov0 = __shfl_xor(v0, d); const int oi0 = __shfl_xor(i0, d);
            const float ov1 = __shfl_xor(v1, d); const int oi1 = __shfl_xor(i1, d);
            const bool aFirst = (v0 > ov0) || (v0 == ov0 && i0 < oi0);
            float n0, n1; int ni0, ni1;
            if (aFirst) {
                n0 = v0; ni0 = i0;
                const bool s = (v1 > ov0) || (v1 == ov0 && i1 < oi0);
                n1 = s ? v1 : ov0; ni1 = s ? i1 : oi0;
            } else {
                n0 = ov0; ni0 = oi0;
                const bool s = (ov1 > v0) || (ov1 == v0 && oi1 < i0);
                n1 = s ? ov1 : v0; ni1 = s ? oi1 : i0;
            }
            v0 = n0; i0 = ni0; v1 = n1; i1 = ni1;
        }
        if (j == 0) {
            const float ex = expf(v1 - v0);
            const float w0 = 1.0f / (1.0f + ex);
            const float w1 = 1.0f - w0;
            out[(size_t)grow * 2 + 0] = w0;
            out[(size_t)grow * 2 + 1] = w1;
            out[IDX_OFF + (size_t)grow * 2 + 0] = (float)i0;
            out[IDX_OFF + (size_t)grow * 2 + 1] = (float)i1;
        }
    }
}

extern "C" void kernel_launch(void* const* d_in, const int* in_sizes, int n_in,
                              void* d_out, int out_size, void* d_ws, size_t ws_size,
                              hipStream_t stream) {
    const float* x     = (const float*)d_in[0];
    const float* Wg    = (const float*)d_in[1];
    const float* Wn    = (const float*)d_in[2];
    const float* noise = (const float*)d_in[3];
    float* out = (float*)d_out;

    _Float16* wh = (_Float16*)d_ws;
    _Float16* wl = wh + WPACK;               // packed matrix is 262144 f16 (512KB)

    split_w_kernel<<<dim3(128), dim3(256), 0, stream>>>(Wg, Wn, wh, wl);
    gating_mfma_kernel<<<dim3(NROWS / BM), dim3(256), 0, stream>>>(x, noise, wh, wl, out);
}

// Round 7
// 68.979 us; speedup vs baseline: 1.2701x; 1.2701x over previous
//
#include <hip/hip_runtime.h>
#include <math.h>

// NoisyTopKGating via fp16x2-split MFMA, LDS-broadcast + global_load_lds 2-phase pipeline.
// BM=64 rows/block, 512 threads (8 waves: 2 row-groups x 4 col-groups), 256 blocks.
// out layout (f32 flat): weights [N,2] @0, indices-as-float [N,2] @32768, clean [N,64] @65536.
// d_ws: Bh packed frags (512KB) @0, Bl packed frags (512KB) @+262144 f16.
// Packed layout (f16 units): [(kc*8 + cg*2 + cf)*512 + lane*8 + j]
//   col = cg*32 + cf*16 + (lane&15),  k = kc*32 + (lane>>4)*8 + j.

constexpr int NROWS = 16384;
constexpr int DDIM  = 2048;
constexpr int EDIM  = 64;
constexpr int BM    = 64;             // rows per block
constexpr int NKS   = 64;             // k-steps of 32
constexpr int LSTR  = 132;            // epilogue LDS stride (floats)
constexpr int IDX_OFF   = NROWS * 2;
constexpr int CLEAN_OFF = NROWS * 4;
constexpr size_t WPACK = 262144;      // f16 elements per packed matrix (128*2048)
constexpr int BUFSZ = 24576;          // staging buffer: X 8KB @0, Bh 8KB @8192, Bl 8KB @16384

typedef _Float16 f16x8 __attribute__((ext_vector_type(8)));
typedef float    f32x4 __attribute__((ext_vector_type(4)));

__device__ __forceinline__ float softplus_f(float z) {
    return fmaxf(z, 0.0f) + log1pf(expf(-fabsf(z)));
}

__device__ __forceinline__ void gload16(const void* g, void* l) {
    __builtin_amdgcn_global_load_lds(
        (const __attribute__((address_space(1))) unsigned int*)g,
        (__attribute__((address_space(3))) unsigned int*)l, 16, 0, 0);
}

// ---------- pre-kernel: split + pack weights into frag-ordered hi/lo ----------
__global__ __launch_bounds__(256) void split_w_kernel(
    const float* __restrict__ Wg, const float* __restrict__ Wn,
    _Float16* __restrict__ wh, _Float16* __restrict__ wl)
{
    const int t    = blockIdx.x * 256 + threadIdx.x;   // 0..32767
    const int grp  = t >> 6;                           // kc*8 + cg*2 + cf  (0..511)
    const int lane = t & 63;
    const int kc   = grp >> 3;
    const int cg   = (grp >> 1) & 3;
    const int cf   = grp & 1;
    const int col  = cg * 32 + cf * 16 + (lane & 15);
    const int k0   = kc * 32 + (lane >> 4) * 8;
    const float* src = (col < 64) ? &Wg[(size_t)col * DDIM + k0]
                                  : &Wn[(size_t)(col - 64) * DDIM + k0];
    const float4 v0 = *reinterpret_cast<const float4*>(src);
    const float4 v1 = *reinterpret_cast<const float4*>(src + 4);
    float vv[8] = {v0.x, v0.y, v0.z, v0.w, v1.x, v1.y, v1.z, v1.w};
    union { _Float16 h[8]; uint4 u; } hh, ll;
    #pragma unroll
    for (int j = 0; j < 8; ++j) {
        hh.h[j] = (_Float16)vv[j];
        ll.h[j] = (_Float16)((vv[j] - (float)hh.h[j]) * 2048.0f);
    }
    const size_t off = (size_t)grp * 512 + lane * 8;
    *reinterpret_cast<uint4*>(&wh[off]) = hh.u;
    *reinterpret_cast<uint4*>(&wl[off]) = ll.u;
}

__device__ __forceinline__ void split8(const float4 a, const float4 b, f16x8& h, f16x8& l) {
    const float v[8] = {a.x, a.y, a.z, a.w, b.x, b.y, b.z, b.w};
    #pragma unroll
    for (int j = 0; j < 8; ++j) {
        const _Float16 hh = (_Float16)v[j];
        h[j] = hh;
        l[j] = (_Float16)((v[j] - (float)hh) * 2048.0f);
    }
}

// ---------- main fused kernel ----------
__global__ __launch_bounds__(512) void gating_mfma_kernel(
    const float* __restrict__ x,
    const float* __restrict__ noise,
    const _Float16* __restrict__ whp,
    const _Float16* __restrict__ wlp,
    float* __restrict__ out)
{
    // 2 staging buffers x 24KB; epilogue reuses as [64][132] f32 (33.8KB).
    __shared__ __align__(16) unsigned char smem[2 * BUFSZ];

    const int tid = threadIdx.x;
    const int row_base = blockIdx.x * BM;
    const int lane = tid & 63;
    const int wid  = tid >> 6;           // 0..7
    const int g    = (lane >> 4) & 3;    // k-group
    const int idx  = lane & 15;
    const int rg   = wid >> 2;           // row-group 0..1
    const int cg   = wid & 3;            // col-group 0..3

    // ---- staging addresses ----
    // x: thread stages 16B of [64][32]f32, LDS slot tid*16, source pre-swizzled q^(row&7)
    const int sr  = tid >> 3;            // row 0..63
    const int sq  = tid & 7;             // 16B slot 0..7
    const int sq2 = sq ^ (sr & 7);
    const float* xsrc = x + (size_t)(row_base + sr) * DDIM + sq2 * 4;
    const char* bhsrc = (const char*)whp + tid * 16;
    const char* blsrc = (const char*)wlp + tid * 16;
    unsigned char* xdst = smem + tid * 16;
    unsigned char* hdst = smem + 8192 + tid * 16;
    unsigned char* ldst = smem + 16384 + tid * 16;

    // ---- A-frag read offsets (swizzled): row = rg*32 + rf*16 + idx, slots g*2+s ----
    int aoff[2][2];
    #pragma unroll
    for (int rf = 0; rf < 2; ++rf) {
        const int row = rg * 32 + rf * 16 + idx;
        #pragma unroll
        for (int s = 0; s < 2; ++s)
            aoff[rf][s] = row * 128 + (((g * 2 + s) ^ (row & 7)) << 4);
    }
    // ---- B-frag read offsets ----
    int bhoff[2], bloff[2];
    #pragma unroll
    for (int cf = 0; cf < 2; ++cf) {
        bhoff[cf] = 8192  + (cg * 2 + cf) * 1024 + lane * 16;
        bloff[cf] = 16384 + (cg * 2 + cf) * 1024 + lane * 16;
    }

    f32x4 accm[2][2], accc[2][2];
    #pragma unroll
    for (int rf = 0; rf < 2; ++rf)
        #pragma unroll
        for (int cf = 0; cf < 2; ++cf) { accm[rf][cf] = (f32x4)0.0f; accc[rf][cf] = (f32x4)0.0f; }

    // ---- prologue: stage k-step 0 into buf0 ----
    gload16(xsrc, xdst);
    gload16(bhsrc, hdst);
    gload16(blsrc, ldst);
    __syncthreads();    // drains vmcnt

    // ---- K loop: 2-phase template (STAGE next -> ds_read cur -> MFMA -> barrier) ----
    for (int t = 0; t < NKS; ++t) {
        const int buf  = (t & 1) * BUFSZ;
        const int nbuf = ((t + 1) & 1) * BUFSZ;
        if (t < NKS - 1) {
            gload16(xsrc + (t + 1) * 32, xdst + nbuf);
            gload16(bhsrc + (size_t)(t + 1) * 8192, hdst + nbuf);
            gload16(blsrc + (size_t)(t + 1) * 8192, ldst + nbuf);
        }

        const float4 a00 = *reinterpret_cast<const float4*>(&smem[buf + aoff[0][0]]);
        const float4 a01 = *reinterpret_cast<const float4*>(&smem[buf + aoff[0][1]]);
        const float4 a10 = *reinterpret_cast<const float4*>(&smem[buf + aoff[1][0]]);
        const float4 a11 = *reinterpret_cast<const float4*>(&smem[buf + aoff[1][1]]);
        const f16x8 Bh0 = *reinterpret_cast<const f16x8*>(&smem[buf + bhoff[0]]);
        const f16x8 Bh1 = *reinterpret_cast<const f16x8*>(&smem[buf + bhoff[1]]);
        const f16x8 Bl0 = *reinterpret_cast<const f16x8*>(&smem[buf + bloff[0]]);
        const f16x8 Bl1 = *reinterpret_cast<const f16x8*>(&smem[buf + bloff[1]]);

        f16x8 Ah0, Al0, Ah1, Al1;
        split8(a00, a01, Ah0, Al0);
        split8(a10, a11, Ah1, Al1);

        accm[0][0] = __builtin_amdgcn_mfma_f32_16x16x32_f16(Ah0, Bh0, accm[0][0], 0, 0, 0);
        accm[0][1] = __builtin_amdgcn_mfma_f32_16x16x32_f16(Ah0, Bh1, accm[0][1], 0, 0, 0);
        accm[1][0] = __builtin_amdgcn_mfma_f32_16x16x32_f16(Ah1, Bh0, accm[1][0], 0, 0, 0);
        accm[1][1] = __builtin_amdgcn_mfma_f32_16x16x32_f16(Ah1, Bh1, accm[1][1], 0, 0, 0);
        accc[0][0] = __builtin_amdgcn_mfma_f32_16x16x32_f16(Al0, Bh0, accc[0][0], 0, 0, 0);
        accc[0][1] = __builtin_amdgcn_mfma_f32_16x16x32_f16(Al0, Bh1, accc[0][1], 0, 0, 0);
        accc[1][0] = __builtin_amdgcn_mfma_f32_16x16x32_f16(Al1, Bh0, accc[1][0], 0, 0, 0);
        accc[1][1] = __builtin_amdgcn_mfma_f32_16x16x32_f16(Al1, Bh1, accc[1][1], 0, 0, 0);
        accc[0][0] = __builtin_amdgcn_mfma_f32_16x16x32_f16(Ah0, Bl0, accc[0][0], 0, 0, 0);
        accc[0][1] = __builtin_amdgcn_mfma_f32_16x16x32_f16(Ah0, Bl1, accc[0][1], 0, 0, 0);
        accc[1][0] = __builtin_amdgcn_mfma_f32_16x16x32_f16(Ah1, Bl0, accc[1][0], 0, 0, 0);
        accc[1][1] = __builtin_amdgcn_mfma_f32_16x16x32_f16(Ah1, Bl1, accc[1][1], 0, 0, 0);

        __syncthreads();
    }

    // ---- epilogue: logits -> LDS [64][132] f32 ----
    float* L = reinterpret_cast<float*>(smem);
    #pragma unroll
    for (int rf = 0; rf < 2; ++rf)
        #pragma unroll
        for (int cf = 0; cf < 2; ++cf) {
            const int col = cg * 32 + cf * 16 + idx;
            #pragma unroll
            for (int q = 0; q < 4; ++q) {
                const int lrow = rg * 32 + rf * 16 + g * 4 + q;
                L[lrow * LSTR + col] = accm[rf][cf][q] + accc[rf][cf][q] * 4.8828125e-4f;
            }
        }
    __syncthreads();

    // ---- fused softplus/noise/top-2/softmax: 8 threads per row, 64 rows ----
    {
        const int row = tid >> 3;
        const int j   = tid & 7;
        const int e0  = j * 8;
        const int grow = row_base + row;

        const float4 c0 = *reinterpret_cast<const float4*>(&L[row * LSTR + e0]);
        const float4 c1 = *reinterpret_cast<const float4*>(&L[row * LSTR + e0 + 4]);
        const float4 s0 = *reinterpret_cast<const float4*>(&L[row * LSTR + 64 + e0]);
        const float4 s1 = *reinterpret_cast<const float4*>(&L[row * LSTR + 64 + e0 + 4]);
        *reinterpret_cast<float4*>(&out[CLEAN_OFF + (size_t)grow * EDIM + e0])     = c0;
        *reinterpret_cast<float4*>(&out[CLEAN_OFF + (size_t)grow * EDIM + e0 + 4]) = c1;

        const float4 z0 = *reinterpret_cast<const float4*>(&noise[(size_t)grow * EDIM + e0]);
        const float4 z1 = *reinterpret_cast<const float4*>(&noise[(size_t)grow * EDIM + e0 + 4]);

        float nv[8];
        nv[0] = fmaf(softplus_f(s0.x), z0.x, c0.x);
        nv[1] = fmaf(softplus_f(s0.y), z0.y, c0.y);
        nv[2] = fmaf(softplus_f(s0.z), z0.z, c0.z);
        nv[3] = fmaf(softplus_f(s0.w), z0.w, c0.w);
        nv[4] = fmaf(softplus_f(s1.x), z1.x, c1.x);
        nv[5] = fmaf(softplus_f(s1.y), z1.y, c1.y);
        nv[6] = fmaf(softplus_f(s1.z), z1.z, c1.z);
        nv[7] = fmaf(softplus_f(s1.w), z1.w, c1.w);

        float v0 = nv[0], v1 = -INFINITY;
        int   i0 = e0,    i1 = -1;
        #pragma unroll
        for (int m = 1; m < 8; ++m) {
            const float v = nv[m]; const int e = e0 + m;
            if (v > v0)      { v1 = v0; i1 = i0; v0 = v; i0 = e; }
            else if (v > v1) { v1 = v;  i1 = e; }
        }
        #pragma unroll
        for (int d = 1; d < 8; d <<= 1) {
            const float ov0 = __shfl_xor(v0, d); const int oi0 = __shfl_xor(i0, d);
            const float ov1 = __shfl_xor(v1, d); const int oi1 = __shfl_xor(i1, d);
            const bool aFirst = (v0 > ov0) || (v0 == ov0 && i0 < oi0);
            float n0, n1; int ni0, ni1;
            if (aFirst) {
                n0 = v0; ni0 = i0;
                const bool s = (v1 > ov0) || (v1 == ov0 && i1 < oi0);
                n1 = s ? v1 : ov0; ni1 = s ? i1 : oi0;
            } else {
                n0 = ov0; ni0 = oi0;
                const bool s = (ov1 > v0) || (ov1 == v0 && oi1 < i0);
                n1 = s ? ov1 : v0; ni1 = s ? oi1 : i0;
            }
            v0 = n0; i0 = ni0; v1 = n1; i1 = ni1;
        }
        if (j == 0) {
            const float ex = expf(v1 - v0);
            const float w0 = 1.0f / (1.0f + ex);
            const float w1 = 1.0f - w0;
            out[(size_t)grow * 2 + 0] = w0;
            out[(size_t)grow * 2 + 1] = w1;
            out[IDX_OFF + (size_t)grow * 2 + 0] = (float)i0;
            out[IDX_OFF + (size_t)grow * 2 + 1] = (float)i1;
        }
    }
}

extern "C" void kernel_launch(void* const* d_in, const int* in_sizes, int n_in,
                              void* d_out, int out_size, void* d_ws, size_t ws_size,
                              hipStream_t stream) {
    const float* x     = (const float*)d_in[0];
    const float* Wg    = (const float*)d_in[1];
    const float* Wn    = (const float*)d_in[2];
    const float* noise = (const float*)d_in[3];
    float* out = (float*)d_out;

    _Float16* wh = (_Float16*)d_ws;
    _Float16* wl = wh + WPACK;               // packed matrix is 262144 f16 (512KB)

    split_w_kernel<<<dim3(128), dim3(256), 0, stream>>>(Wg, Wn, wh, wl);
    gating_mfma_kernel<<<dim3(NROWS / BM), dim3(512), 0, stream>>>(x, noise, wh, wl, out);
}

// Round 8
// 53.924 us; speedup vs baseline: 1.6246x; 1.2792x over previous
//
#include <hip/hip_runtime.h>
#include <math.h>

// NoisyTopKGating via fp16x2-split MFMA, LDS-broadcast + global_load_lds pipeline
// with counted vmcnt (T3+T4): 4 staging buffers, prefetch distance 2, never vmcnt(0)
// in the main loop. BM=64 rows/block, 512 threads (8 waves: 2 rg x 4 cg), 256 blocks.
// out layout (f32 flat): weights [N,2] @0, indices-as-float [N,2] @32768, clean [N,64] @65536.
// d_ws: Bh packed frags (512KB) @0, Bl packed frags (512KB) @+262144 f16.
// Packed layout (f16 units): [(kc*8 + cg*2 + cf)*512 + lane*8 + j]
//   col = cg*32 + cf*16 + (lane&15),  k = kc*32 + (lane>>4)*8 + j.

constexpr int NROWS = 16384;
constexpr int DDIM  = 2048;
constexpr int EDIM  = 64;
constexpr int BM    = 64;             // rows per block
constexpr int NKS   = 64;             // k-steps of 32
constexpr int LSTR  = 132;            // epilogue LDS stride (floats)
constexpr int IDX_OFF   = NROWS * 2;
constexpr int CLEAN_OFF = NROWS * 4;
constexpr size_t WPACK = 262144;      // f16 elements per packed matrix (128*2048)
constexpr int BUFSZ = 24576;          // staging buffer: X 8KB @0, Bh 8KB @8192, Bl 8KB @16384
constexpr int NBUF  = 4;              // 96KB LDS total (dynamic)

typedef _Float16 f16x8 __attribute__((ext_vector_type(8)));
typedef float    f32x4 __attribute__((ext_vector_type(4)));

__device__ __forceinline__ float softplus_f(float z) {
    return fmaxf(z, 0.0f) + log1pf(expf(-fabsf(z)));
}

__device__ __forceinline__ void gload16(const void* g, void* l) {
    __builtin_amdgcn_global_load_lds(
        (const __attribute__((address_space(1))) unsigned int*)g,
        (__attribute__((address_space(3))) unsigned int*)l, 16, 0, 0);
}

// ---------- pre-kernel: split + pack weights into frag-ordered hi/lo ----------
__global__ __launch_bounds__(256) void split_w_kernel(
    const float* __restrict__ Wg, const float* __restrict__ Wn,
    _Float16* __restrict__ wh, _Float16* __restrict__ wl)
{
    const int t    = blockIdx.x * 256 + threadIdx.x;   // 0..32767
    const int grp  = t >> 6;                           // kc*8 + cg*2 + cf  (0..511)
    const int lane = t & 63;
    const int kc   = grp >> 3;
    const int cg   = (grp >> 1) & 3;
    const int cf   = grp & 1;
    const int col  = cg * 32 + cf * 16 + (lane & 15);
    const int k0   = kc * 32 + (lane >> 4) * 8;
    const float* src = (col < 64) ? &Wg[(size_t)col * DDIM + k0]
                                  : &Wn[(size_t)(col - 64) * DDIM + k0];
    const float4 v0 = *reinterpret_cast<const float4*>(src);
    const float4 v1 = *reinterpret_cast<const float4*>(src + 4);
    float vv[8] = {v0.x, v0.y, v0.z, v0.w, v1.x, v1.y, v1.z, v1.w};
    union { _Float16 h[8]; uint4 u; } hh, ll;
    #pragma unroll
    for (int j = 0; j < 8; ++j) {
        hh.h[j] = (_Float16)vv[j];
        ll.h[j] = (_Float16)((vv[j] - (float)hh.h[j]) * 2048.0f);
    }
    const size_t off = (size_t)grp * 512 + lane * 8;
    *reinterpret_cast<uint4*>(&wh[off]) = hh.u;
    *reinterpret_cast<uint4*>(&wl[off]) = ll.u;
}

__device__ __forceinline__ void split8(const float4 a, const float4 b, f16x8& h, f16x8& l) {
    const float v[8] = {a.x, a.y, a.z, a.w, b.x, b.y, b.z, b.w};
    #pragma unroll
    for (int j = 0; j < 8; ++j) {
        const _Float16 hh = (_Float16)v[j];
        h[j] = hh;
        l[j] = (_Float16)((v[j] - (float)hh) * 2048.0f);
    }
}

// ---------- main fused kernel ----------
__global__ __launch_bounds__(512, 1) void gating_mfma_kernel(
    const float* __restrict__ x,
    const float* __restrict__ noise,
    const _Float16* __restrict__ whp,
    const _Float16* __restrict__ wlp,
    float* __restrict__ out)
{
    extern __shared__ __align__(16) unsigned char smem[];   // NBUF*BUFSZ = 96KB

    const int tid = threadIdx.x;
    const int row_base = blockIdx.x * BM;
    const int lane = tid & 63;
    const int wid  = tid >> 6;           // 0..7
    const int g    = (lane >> 4) & 3;    // k-group
    const int idx  = lane & 15;
    const int rg   = wid >> 2;           // row-group 0..1
    const int cg   = wid & 3;            // col-group 0..3

    // ---- staging addresses ----
    // x: thread stages 16B of [64][32]f32; LDS dest linear tid*16; source pre-swizzled
    const int sr  = tid >> 3;            // row 0..63
    const int sq  = tid & 7;             // 16B slot 0..7
    const int sq2 = sq ^ (sr & 7);
    const float* xsrc = x + (size_t)(row_base + sr) * DDIM + sq2 * 4;
    const char* bhsrc = (const char*)whp + tid * 16;
    const char* blsrc = (const char*)wlp + tid * 16;

    // ---- A-frag read offsets (swizzled): row = rg*32 + rf*16 + idx, slots g*2+s ----
    int aoff[2][2];
    #pragma unroll
    for (int rf = 0; rf < 2; ++rf) {
        const int row = rg * 32 + rf * 16 + idx;
        #pragma unroll
        for (int s = 0; s < 2; ++s)
            aoff[rf][s] = row * 128 + (((g * 2 + s) ^ (row & 7)) << 4);
    }
    // ---- B-frag read offsets ----
    int bhoff[2], bloff[2];
    #pragma unroll
    for (int cf = 0; cf < 2; ++cf) {
        bhoff[cf] = 8192  + (cg * 2 + cf) * 1024 + lane * 16;
        bloff[cf] = 16384 + (cg * 2 + cf) * 1024 + lane * 16;
    }

    f32x4 accm[2][2], accc[2][2];
    #pragma unroll
    for (int rf = 0; rf < 2; ++rf)
        #pragma unroll
        for (int cf = 0; cf < 2; ++cf) { accm[rf][cf] = (f32x4)0.0f; accc[rf][cf] = (f32x4)0.0f; }

    auto stage = [&](int u) {
        const int b = (u & (NBUF - 1)) * BUFSZ;
        gload16(xsrc + u * 32,                 smem + b + tid * 16);
        gload16(bhsrc + (size_t)u * 8192,      smem + b + 8192 + tid * 16);
        gload16(blsrc + (size_t)u * 8192,      smem + b + 16384 + tid * 16);
    };

    auto computeStep = [&](int b) {
        const float4 a00 = *reinterpret_cast<const float4*>(&smem[b + aoff[0][0]]);
        const float4 a01 = *reinterpret_cast<const float4*>(&smem[b + aoff[0][1]]);
        const float4 a10 = *reinterpret_cast<const float4*>(&smem[b + aoff[1][0]]);
        const float4 a11 = *reinterpret_cast<const float4*>(&smem[b + aoff[1][1]]);
        const f16x8 Bh0 = *reinterpret_cast<const f16x8*>(&smem[b + bhoff[0]]);
        const f16x8 Bh1 = *reinterpret_cast<const f16x8*>(&smem[b + bhoff[1]]);
        const f16x8 Bl0 = *reinterpret_cast<const f16x8*>(&smem[b + bloff[0]]);
        const f16x8 Bl1 = *reinterpret_cast<const f16x8*>(&smem[b + bloff[1]]);

        f16x8 Ah0, Al0, Ah1, Al1;
        split8(a00, a01, Ah0, Al0);
        split8(a10, a11, Ah1, Al1);

        accm[0][0] = __builtin_amdgcn_mfma_f32_16x16x32_f16(Ah0, Bh0, accm[0][0], 0, 0, 0);
        accm[0][1] = __builtin_amdgcn_mfma_f32_16x16x32_f16(Ah0, Bh1, accm[0][1], 0, 0, 0);
        accm[1][0] = __builtin_amdgcn_mfma_f32_16x16x32_f16(Ah1, Bh0, accm[1][0], 0, 0, 0);
        accm[1][1] = __builtin_amdgcn_mfma_f32_16x16x32_f16(Ah1, Bh1, accm[1][1], 0, 0, 0);
        accc[0][0] = __builtin_amdgcn_mfma_f32_16x16x32_f16(Al0, Bh0, accc[0][0], 0, 0, 0);
        accc[0][1] = __builtin_amdgcn_mfma_f32_16x16x32_f16(Al0, Bh1, accc[0][1], 0, 0, 0);
        accc[1][0] = __builtin_amdgcn_mfma_f32_16x16x32_f16(Al1, Bh0, accc[1][0], 0, 0, 0);
        accc[1][1] = __builtin_amdgcn_mfma_f32_16x16x32_f16(Al1, Bh1, accc[1][1], 0, 0, 0);
        accc[0][0] = __builtin_amdgcn_mfma_f32_16x16x32_f16(Ah0, Bl0, accc[0][0], 0, 0, 0);
        accc[0][1] = __builtin_amdgcn_mfma_f32_16x16x32_f16(Ah0, Bl1, accc[0][1], 0, 0, 0);
        accc[1][0] = __builtin_amdgcn_mfma_f32_16x16x32_f16(Ah1, Bl0, accc[1][0], 0, 0, 0);
        accc[1][1] = __builtin_amdgcn_mfma_f32_16x16x32_f16(Ah1, Bl1, accc[1][1], 0, 0, 0);
    };

    // ---- prologue: buffers 0 and 1 in flight ----
    stage(0);
    stage(1);

    // ---- main loop: counted vmcnt(6) — 2 newer k-steps (6 loads) stay in flight ----
    for (int t = 0; t < NKS - 2; ++t) {
        stage(t + 2);
        asm volatile("s_waitcnt vmcnt(6)" ::: "memory");
        __builtin_amdgcn_s_barrier();
        __builtin_amdgcn_sched_barrier(0);
        computeStep((t & (NBUF - 1)) * BUFSZ);
    }
    // ---- tail: t = NKS-2 (wait its 3 loads; NKS-1's 3 still in flight) ----
    asm volatile("s_waitcnt vmcnt(3)" ::: "memory");
    __builtin_amdgcn_s_barrier();
    __builtin_amdgcn_sched_barrier(0);
    computeStep(((NKS - 2) & (NBUF - 1)) * BUFSZ);
    // ---- tail: t = NKS-1 ----
    asm volatile("s_waitcnt vmcnt(0)" ::: "memory");
    __builtin_amdgcn_s_barrier();
    __builtin_amdgcn_sched_barrier(0);
    computeStep(((NKS - 1) & (NBUF - 1)) * BUFSZ);

    __builtin_amdgcn_s_barrier();    // all ds_reads of last buffer done before epilogue reuse

    // ---- epilogue: logits -> LDS [64][132] f32 ----
    float* L = reinterpret_cast<float*>(smem);
    #pragma unroll
    for (int rf = 0; rf < 2; ++rf)
        #pragma unroll
        for (int cf = 0; cf < 2; ++cf) {
            const int col = cg * 32 + cf * 16 + idx;
            #pragma unroll
            for (int q = 0; q < 4; ++q) {
                const int lrow = rg * 32 + rf * 16 + g * 4 + q;
                L[lrow * LSTR + col] = accm[rf][cf][q] + accc[rf][cf][q] * 4.8828125e-4f;
            }
        }
    __syncthreads();

    // ---- fused softplus/noise/top-2/softmax: 8 threads per row, 64 rows ----
    {
        const int row = tid >> 3;
        const int j   = tid & 7;
        const int e0  = j * 8;
        const int grow = row_base + row;

        const float4 c0 = *reinterpret_cast<const float4*>(&L[row * LSTR + e0]);
        const float4 c1 = *reinterpret_cast<const float4*>(&L[row * LSTR + e0 + 4]);
        const float4 s0 = *reinterpret_cast<const float4*>(&L[row * LSTR + 64 + e0]);
        const float4 s1 = *reinterpret_cast<const float4*>(&L[row * LSTR + 64 + e0 + 4]);
        *reinterpret_cast<float4*>(&out[CLEAN_OFF + (size_t)grow * EDIM + e0])     = c0;
        *reinterpret_cast<float4*>(&out[CLEAN_OFF + (size_t)grow * EDIM + e0 + 4]) = c1;

        const float4 z0 = *reinterpret_cast<const float4*>(&noise[(size_t)grow * EDIM + e0]);
        const float4 z1 = *reinterpret_cast<const float4*>(&noise[(size_t)grow * EDIM + e0 + 4]);

        float nv[8];
        nv[0] = fmaf(softplus_f(s0.x), z0.x, c0.x);
        nv[1] = fmaf(softplus_f(s0.y), z0.y, c0.y);
        nv[2] = fmaf(softplus_f(s0.z), z0.z, c0.z);
        nv[3] = fmaf(softplus_f(s0.w), z0.w, c0.w);
        nv[4] = fmaf(softplus_f(s1.x), z1.x, c1.x);
        nv[5] = fmaf(softplus_f(s1.y), z1.y, c1.y);
        nv[6] = fmaf(softplus_f(s1.z), z1.z, c1.z);
        nv[7] = fmaf(softplus_f(s1.w), z1.w, c1.w);

        float v0 = nv[0], v1 = -INFINITY;
        int   i0 = e0,    i1 = -1;
        #pragma unroll
        for (int m = 1; m < 8; ++m) {
            const float v = nv[m]; const int e = e0 + m;
            if (v > v0)      { v1 = v0; i1 = i0; v0 = v; i0 = e; }
            else if (v > v1) { v1 = v;  i1 = e; }
        }
        #pragma unroll
        for (int d = 1; d < 8; d <<= 1) {
            const float ov0 = __shfl_xor(v0, d); const int oi0 = __shfl_xor(i0, d);
            const float ov1 = __shfl_xor(v1, d); const int oi1 = __shfl_xor(i1, d);
            const bool aFirst = (v0 > ov0) || (v0 == ov0 && i0 < oi0);
            float n0, n1; int ni0, ni1;
            if (aFirst) {
                n0 = v0; ni0 = i0;
                const bool s = (v1 > ov0) || (v1 == ov0 && i1 < oi0);
                n1 = s ? v1 : ov0; ni1 = s ? i1 : oi0;
            } else {
                n0 = ov0; ni0 = oi0;
                const bool s = (ov1 > v0) || (ov1 == v0 && oi1 < i0);
                n1 = s ? ov1 : v0; ni1 = s ? oi1 : i0;
            }
            v0 = n0; i0 = ni0; v1 = n1; i1 = ni1;
        }
        if (j == 0) {
            const float ex = expf(v1 - v0);
            const float w0 = 1.0f / (1.0f + ex);
            const float w1 = 1.0f - w0;
            out[(size_t)grow * 2 + 0] = w0;
            out[(size_t)grow * 2 + 1] = w1;
            out[IDX_OFF + (size_t)grow * 2 + 0] = (float)i0;
            out[IDX_OFF + (size_t)grow * 2 + 1] = (float)i1;
        }
    }
}

extern "C" void kernel_launch(void* const* d_in, const int* in_sizes, int n_in,
                              void* d_out, int out_size, void* d_ws, size_t ws_size,
                              hipStream_t stream) {
    const float* x     = (const float*)d_in[0];
    const float* Wg    = (const float*)d_in[1];
    const float* Wn    = (const float*)d_in[2];
    const float* noise = (const float*)d_in[3];
    float* out = (float*)d_out;

    _Float16* wh = (_Float16*)d_ws;
    _Float16* wl = wh + WPACK;               // packed matrix is 262144 f16 (512KB)

    split_w_kernel<<<dim3(128), dim3(256), 0, stream>>>(Wg, Wn, wh, wl);
    gating_mfma_kernel<<<dim3(NROWS / BM), dim3(512), NBUF * BUFSZ, stream>>>(x, noise, wh, wl, out);
}